// Round 8
// baseline (220.030 us; speedup 1.0000x reference)
//
#include <hip/hip_runtime.h>
#include <math.h>

#define NN 50000
#define EE 800000
#define ETOT 850000
#define NEG 0.2f
#define CAP 64      // per-node edge bucket capacity; P(deg>64) ~ 1e-18 for Poisson(16)+1
#define NBLK 782    // gemm blocks (64 rows each)
#define NTILE 3128  // 16-row A tiles = NBLK*4

typedef unsigned short ushort_t;
typedef __attribute__((ext_vector_type(8))) short bf16x8;   // 8 bf16 (4 VGPRs)
typedef __attribute__((ext_vector_type(4))) float f32x4;    // MFMA accumulator

__device__ __forceinline__ unsigned f2bf(float f) {
    unsigned u = __float_as_uint(f);
    return (u + 0x7FFFu + ((u >> 16) & 1u)) >> 16;
}
// packed fp32x2 -> bf16x2 (RNE), single instruction
__device__ __forceinline__ unsigned cvtpk(float lo, float hi) {
    unsigned r;
    asm("v_cvt_pk_bf16_f32 %0, %1, %2" : "=v"(r) : "v"(lo), "v"(hi));
    return r;
}
__device__ __forceinline__ float blo(unsigned u) { return __uint_as_float(u << 16); }
__device__ __forceinline__ float bhi(unsigned u) { return __uint_as_float(u & 0xffff0000u); }

__device__ __forceinline__ int load_idx(const void* ei, int f64, long long pos) {
    return f64 ? (int)((const long long*)ei)[pos] : ((const int*)ei)[pos];
}

// bucketed fill: esrc[dst*CAP + pos] (ushort; NN < 65536), cursor[] = degree.
__global__ void k_fill(const void* ei, const int* __restrict__ flag,
                       int* cursor, ushort_t* __restrict__ esrc) {
    int e = blockIdx.x * blockDim.x + threadIdx.x;
    if (e >= ETOT) return;
    int f = *flag;
    int src, dst;
    if (e < EE) {
        src = load_idx(ei, f, e);
        dst = load_idx(ei, f, (long long)EE + e);
    } else {
        src = dst = e - EE;
    }
    int pos = atomicAdd(&cursor[dst], 1);
    if (pos < CAP) esrc[dst * CAP + pos] = (ushort_t)src;
}

// Combined prep:
//  blocks [0, NTILE): swizzle x fp32 -> Af bf16 in A-fragment lane order.
//  blocks [NTILE, ...): W1 -> Wf (MFMA B lane order), b1/W2 -> per-(head,slot)
//    permuted b1s/W2s matching the uint4 head-slice layout, edge width detect.
// Slice layout: node slice (128B) = uint2[16]; uint2[lr] = cols {lr,16+lr,32+lr,48+lr}
// of the head. As uint4 slot s: features {2s,16+2s,32+2s,48+2s, 2s+1,16+2s+1,32+2s+1,48+2s+1}.
__global__ __launch_bounds__(256) void k_prep(const float* __restrict__ x,
                                              const float* __restrict__ W,
                                              const float* __restrict__ b1,
                                              const float* __restrict__ W2,
                                              const void* ei,
                                              bf16x8* __restrict__ Af,
                                              ushort_t* __restrict__ Wf,
                                              float* __restrict__ b1s,
                                              float* __restrict__ W2s,
                                              int* __restrict__ flag) {
    int bid = blockIdx.x, t = threadIdx.x;
    if (bid < NTILE) {
        int kt = t >> 6, lg = (t >> 4) & 3, lr = t & 15;
        int row = bid * 16 + lr;
        if (row >= NN) row = NN - 1;
        const float4* p = (const float4*)(x + (size_t)row * 128 + kt * 32 + lg * 8);
        float4 a = p[0], b = p[1];
        union { unsigned u[4]; bf16x8 v; } r;
        r.u[0] = cvtpk(a.x, a.y);
        r.u[1] = cvtpk(a.z, a.w);
        r.u[2] = cvtpk(b.x, b.y);
        r.u[3] = cvtpk(b.z, b.w);
        Af[(size_t)bid * 256 + t] = r.v;
        return;
    }
    int idx = (bid - NTILE) * 256 + t;
    if (idx < 32768) {
        int e = idx & 7, l = (idx >> 3) & 63, ct = (idx >> 9) & 15, kt = idx >> 13;
        int k = kt * 32 + (l >> 4) * 8 + e;
        int col = ct * 16 + (l & 15);
        Wf[idx] = (ushort_t)f2bf(W[k * 256 + col]);
    } else if (idx < 32768 + 256) {
        int c = idx - 32768;             // [head(2)][slot(3)][kk(3)]
        int head = c >> 6, slot = (c >> 3) & 7, kk = c & 7;
        int f = (kk < 4) ? (kk * 16 + 2 * slot) : ((kk - 4) * 16 + 2 * slot + 1);
        b1s[c] = b1[head * 64 + f];
        W2s[c] = W2[head * 64 + f];
    } else if (idx == 32768 + 256) {
        const long long* p = (const long long*)ei;
        int ok = 1;
        for (int i = 0; i < 64; ++i) {
            long long v = p[i];
            if (v < 0 || v >= NN) ok = 0;
        }
        *flag = ok;  // 1 -> int64, 0 -> int32
    }
}

// h = x @ W1 via mfma_f32_16x16x32_bf16. Block: 4 waves, 64 rows x 256 cols;
// wave w == head w. Epilogue: HEAD-MAJOR packed store h1h[head][row][uint2 x16]
// + per-head scores sSh/sDh [head][node].
__global__ __launch_bounds__(256) void k_gemm_mfma(
    const bf16x8* __restrict__ Af, const ushort_t* __restrict__ Wf,
    const float* __restrict__ aS, const float* __restrict__ aD,
    uint2* __restrict__ h1h, float* __restrict__ sSh, float* __restrict__ sDh) {
    int t = threadIdx.x, wid = t >> 6, l = t & 63;
    int lg = l >> 4, lr = l & 15;
    int r0 = blockIdx.x * 64;
    int tile0 = blockIdx.x * 4;
    int c0 = wid * 64;
    const bf16x8* Bv = (const bf16x8*)Wf;

    f32x4 acc[4][4] = {};
#pragma unroll
    for (int kt = 0; kt < 4; ++kt) {
        bf16x8 a[4];
#pragma unroll
        for (int rt = 0; rt < 4; ++rt)
            a[rt] = Af[(size_t)(((tile0 + rt) * 4 + kt) * 4 + lg) * 16 + lr];
#pragma unroll
        for (int ct = 0; ct < 4; ++ct) {
            bf16x8 b = Bv[(size_t)((kt * 16 + wid * 4 + ct) * 64 + l)];
#pragma unroll
            for (int rt = 0; rt < 4; ++rt)
                acc[rt][ct] = __builtin_amdgcn_mfma_f32_16x16x32_bf16(a[rt], b, acc[rt][ct], 0, 0, 0);
        }
    }
    // epilogue. C/D layout: col = c0+ct*16+lr, row = r0+rt*16+lg*4+q
    float aSl[4], aDl[4];
#pragma unroll
    for (int ct = 0; ct < 4; ++ct) {
        aSl[ct] = aS[c0 + ct * 16 + lr];
        aDl[ct] = aD[c0 + ct * 16 + lr];
    }
#pragma unroll
    for (int rt = 0; rt < 4; ++rt) {
#pragma unroll
        for (int q = 0; q < 4; ++q) {
            int row = r0 + rt * 16 + lg * 4 + q;
            bool ok = row < NN;
            float v0 = acc[rt][0][q], v1 = acc[rt][1][q];
            float v2 = acc[rt][2][q], v3 = acc[rt][3][q];
            float p = v0 * aSl[0] + v1 * aSl[1] + v2 * aSl[2] + v3 * aSl[3];
            float dd = v0 * aDl[0] + v1 * aDl[1] + v2 * aDl[2] + v3 * aDl[3];
            uint2 u;
            u.x = cvtpk(v0, v1);
            u.y = cvtpk(v2, v3);
            if (ok) h1h[((size_t)wid * NN + row) * 16 + lr] = u;
#pragma unroll
            for (int k = 8; k >= 1; k >>= 1) {
                p += __shfl_xor(p, k, 64);
                dd += __shfl_xor(dd, k, 64);
            }
            if (ok && lr == 0) {
                sSh[wid * NN + row] = p;
                sDh[wid * NN + row] = dd;
            }
        }
    }
}

// layer-1 aggregation, HEAD-SPLIT: one wave per (dst node, head).
// blockIdx%8 -> XCD (measured round-robin); head = (blockIdx%8)>>1 pins each
// head's 6.4MB h-slice to an XCD pair (per-XCD L2 footprint 4x smaller).
// Pass 1: per-lane edge score (this head only) -> max/exp/sum -> alpha in LDS.
// Pass 2: 8 lanes x uint4 per edge slice; 8 edges per wave-load, x2 unrolled.
// Epilogue: +b1 slice -> ELU -> dot W2 slice -> reduce -> atomicAdd g[n].
__global__ __launch_bounds__(256) void k_agg1(
    const int* __restrict__ cursor, const ushort_t* __restrict__ esrc,
    const uint4* __restrict__ h1h, const float* __restrict__ sSh,
    const float* __restrict__ sDh, const float* __restrict__ b1s,
    const float* __restrict__ W2s, float* __restrict__ g) {
    __shared__ float al_lds[4][CAP];
    __shared__ int s_lds[4][CAP];
    int b = blockIdx.x;
    int xcd = b & 7, head = xcd >> 1, sub = xcd & 1;
    int grp = b >> 3;
    int wid = threadIdx.x >> 6, lane = threadIdx.x & 63;
    int n = grp * 8 + sub * 4 + wid;   // grid sized so n < NN always
    int d = cursor[n];
    if (d > CAP) d = CAP;
    int dp = (d + 15) & ~15;  // pad to x16 (two 8-edge waves per iter)
    float sdn = sDh[head * NN + n];
    float e = -1e30f;
    int s = 0;
    if (lane < d) {
        s = esrc[n * CAP + lane];
        e = sSh[head * NN + s] + sdn;
        e = e > 0.f ? e : NEG * e;
    }
    float m = e;
#pragma unroll
    for (int k = 32; k >= 1; k >>= 1) m = fmaxf(m, __shfl_xor(m, k, 64));
    float xv = __expf(e - m);   // inactive lanes -> 0
    float q = xv;
#pragma unroll
    for (int k = 32; k >= 1; k >>= 1) q += __shfl_xor(q, k, 64);
    al_lds[wid][lane] = xv / q;  // pads: 0
    s_lds[wid][lane] = s;
    // pass 2: slot = lane&7 (uint4 within 128B slice), eg = lane>>3 (edge group)
    int slot = lane & 7, eg = lane >> 3;
    const uint4* hp = h1h + (size_t)head * NN * 8 + slot;
    float a0 = 0.f, a1 = 0.f, a2 = 0.f, a3 = 0.f;
    float a4 = 0.f, a5 = 0.f, a6 = 0.f, a7 = 0.f;
    for (int j = 0; j < dp; j += 16) {
        int iA = j + eg, iB = j + 8 + eg;
        float wA = al_lds[wid][iA];
        float wB = al_lds[wid][iB];
        int sA = s_lds[wid][iA];
        int sB = s_lds[wid][iB];
        uint4 uA = hp[(size_t)sA * 8];
        uint4 uB = hp[(size_t)sB * 8];
        a0 = fmaf(wA, blo(uA.x), a0); a1 = fmaf(wA, bhi(uA.x), a1);
        a2 = fmaf(wA, blo(uA.y), a2); a3 = fmaf(wA, bhi(uA.y), a3);
        a4 = fmaf(wA, blo(uA.z), a4); a5 = fmaf(wA, bhi(uA.z), a5);
        a6 = fmaf(wA, blo(uA.w), a6); a7 = fmaf(wA, bhi(uA.w), a7);
        a0 = fmaf(wB, blo(uB.x), a0); a1 = fmaf(wB, bhi(uB.x), a1);
        a2 = fmaf(wB, blo(uB.y), a2); a3 = fmaf(wB, bhi(uB.y), a3);
        a4 = fmaf(wB, blo(uB.z), a4); a5 = fmaf(wB, bhi(uB.z), a5);
        a6 = fmaf(wB, blo(uB.w), a6); a7 = fmaf(wB, bhi(uB.w), a7);
    }
    // combine the 8 edge groups (same slot)
    a0 += __shfl_xor(a0, 8, 64);  a0 += __shfl_xor(a0, 16, 64); a0 += __shfl_xor(a0, 32, 64);
    a1 += __shfl_xor(a1, 8, 64);  a1 += __shfl_xor(a1, 16, 64); a1 += __shfl_xor(a1, 32, 64);
    a2 += __shfl_xor(a2, 8, 64);  a2 += __shfl_xor(a2, 16, 64); a2 += __shfl_xor(a2, 32, 64);
    a3 += __shfl_xor(a3, 8, 64);  a3 += __shfl_xor(a3, 16, 64); a3 += __shfl_xor(a3, 32, 64);
    a4 += __shfl_xor(a4, 8, 64);  a4 += __shfl_xor(a4, 16, 64); a4 += __shfl_xor(a4, 32, 64);
    a5 += __shfl_xor(a5, 8, 64);  a5 += __shfl_xor(a5, 16, 64); a5 += __shfl_xor(a5, 32, 64);
    a6 += __shfl_xor(a6, 8, 64);  a6 += __shfl_xor(a6, 16, 64); a6 += __shfl_xor(a6, 32, 64);
    a7 += __shfl_xor(a7, 8, 64);  a7 += __shfl_xor(a7, 16, 64); a7 += __shfl_xor(a7, 32, 64);
    // epilogue on the 8 features of (head, slot)
    const float4* bp = (const float4*)(b1s + head * 64 + slot * 8);
    const float4* wp = (const float4*)(W2s + head * 64 + slot * 8);
    float4 bA = bp[0], bB = bp[1];
    float4 wA4 = wp[0], wB4 = wp[1];
    float o0 = a0 + bA.x, o1 = a1 + bA.y, o2 = a2 + bA.z, o3 = a3 + bA.w;
    float o4 = a4 + bB.x, o5 = a5 + bB.y, o6 = a6 + bB.z, o7 = a7 + bB.w;
    o0 = o0 > 0.f ? o0 : expm1f(o0);
    o1 = o1 > 0.f ? o1 : expm1f(o1);
    o2 = o2 > 0.f ? o2 : expm1f(o2);
    o3 = o3 > 0.f ? o3 : expm1f(o3);
    o4 = o4 > 0.f ? o4 : expm1f(o4);
    o5 = o5 > 0.f ? o5 : expm1f(o5);
    o6 = o6 > 0.f ? o6 : expm1f(o6);
    o7 = o7 > 0.f ? o7 : expm1f(o7);
    float part = o0 * wA4.x + o1 * wA4.y + o2 * wA4.z + o3 * wA4.w
               + o4 * wB4.x + o5 * wB4.y + o6 * wB4.z + o7 * wB4.w;
    part += __shfl_xor(part, 1, 64);
    part += __shfl_xor(part, 2, 64);
    part += __shfl_xor(part, 4, 64);
    if (lane == 0) atomicAdd(&g[n], part);
}

// layer 2: scalar attention, one wave per dst node, one edge per lane.
__global__ __launch_bounds__(256) void k_layer2(
    const int* __restrict__ cursor, const ushort_t* __restrict__ esrc,
    const float* __restrict__ g, const float* __restrict__ aS2,
    const float* __restrict__ aD2, const float* __restrict__ b2,
    float* __restrict__ out) {
    int wid = threadIdx.x >> 6, lane = threadIdx.x & 63;
    int n = blockIdx.x * 4 + wid;
    if (n >= NN) return;
    int d = cursor[n];
    if (d > CAP) d = CAP;
    float aS = aS2[0], aD = aD2[0];
    float dn = g[n] * aD;
    float gv = 0.f, e = -1e30f;
    if (lane < d) {
        gv = g[esrc[n * CAP + lane]];
        e = gv * aS + dn;
        e = e > 0.f ? e : NEG * e;
    }
    float m = e;
#pragma unroll
    for (int k = 32; k >= 1; k >>= 1) m = fmaxf(m, __shfl_xor(m, k, 64));
    float ex = (lane < d) ? __expf(e - m) : 0.f;
    float den = ex, ws = ex * gv;
#pragma unroll
    for (int k = 32; k >= 1; k >>= 1) {
        den += __shfl_xor(den, k, 64);
        ws += __shfl_xor(ws, k, 64);
    }
    if (lane == 0) out[n] = ws / den + b2[0];
}

extern "C" void kernel_launch(void* const* d_in, const int* in_sizes, int n_in,
                              void* d_out, int out_size, void* d_ws, size_t ws_size,
                              hipStream_t stream) {
    const float* x   = (const float*)d_in[0];
    const void*  ei  = d_in[1];
    const float* W1  = (const float*)d_in[2];
    const float* aS1 = (const float*)d_in[3];
    const float* aD1 = (const float*)d_in[4];
    const float* b1  = (const float*)d_in[5];
    const float* W2  = (const float*)d_in[6];
    const float* aS2 = (const float*)d_in[7];
    const float* aD2 = (const float*)d_in[8];
    const float* b2  = (const float*)d_in[9];
    float* out = (float*)d_out;

    char* w = (char*)d_ws;
    size_t off = 0;
    auto take = [&](size_t bytes) {
        char* p = w + off;
        off = (off + bytes + 255) & ~(size_t)255;
        return p;
    };
    int*      flag   = (int*)take(4);
    int*      cursor = (int*)take((size_t)NN * 4);
    ushort_t* esrc   = (ushort_t*)take((size_t)NN * CAP * 2);
    float*    sSh    = (float*)take((size_t)4 * NN * 4);
    float*    sDh    = (float*)take((size_t)4 * NN * 4);
    float*    g      = (float*)take((size_t)NN * 4);
    void*     h1h    = take((size_t)4 * NN * 128);  // head-major bf16 slices
    bf16x8*   Af     = (bf16x8*)take((size_t)NTILE * 256 * 16);
    ushort_t* Wf     = (ushort_t*)take((size_t)128 * 256 * 2);
    float*    b1s    = (float*)take((size_t)256 * 4);
    float*    W2s    = (float*)take((size_t)256 * 4);
    (void)ws_size; (void)in_sizes; (void)n_in; (void)out_size;

    hipMemsetAsync(cursor, 0, (size_t)NN * 4, stream);
    hipMemsetAsync(g, 0, (size_t)NN * 4, stream);
    k_prep<<<NTILE + 130, 256, 0, stream>>>(x, W1, b1, W2, ei, Af, Wf, b1s, W2s, flag);
    k_fill<<<(ETOT + 255) / 256, 256, 0, stream>>>(ei, flag, cursor, esrc);
    k_gemm_mfma<<<NBLK, 256, 0, stream>>>(Af, Wf, aS1, aD1, (uint2*)h1h, sSh, sDh);
    k_agg1<<<(NN / 4) * 4, 256, 0, stream>>>(cursor, esrc, (const uint4*)h1h, sSh, sDh, b1s, W2s, g);
    k_layer2<<<(NN + 3) / 4, 256, 0, stream>>>(cursor, esrc, g, aS2, aD2, b2, out);
}

// Round 10
// 203.817 us; speedup vs baseline: 1.0795x; 1.0795x over previous
//
#include <hip/hip_runtime.h>
#include <hip/hip_fp16.h>
#include <math.h>

#define NN 50000
#define EE 800000
#define ETOT 850000
#define NEG 0.2f
#define CAP 64      // per-node edge bucket capacity; P(deg>64) ~ 1e-18 for Poisson(16)+1
#define NBLK 782    // gemm blocks (64 rows each)
#define NTILE 3128  // 16-row A tiles = NBLK*4

typedef unsigned short ushort_t;
typedef __attribute__((ext_vector_type(8))) short bf16x8;   // 8 bf16 (4 VGPRs)
typedef __attribute__((ext_vector_type(4))) float f32x4;    // MFMA accumulator

__device__ __forceinline__ unsigned f2bf(float f) {
    unsigned u = __float_as_uint(f);
    return (u + 0x7FFFu + ((u >> 16) & 1u)) >> 16;
}
// packed fp32x2 -> bf16x2 (RNE), single instruction
__device__ __forceinline__ unsigned cvtpk(float lo, float hi) {
    unsigned r;
    asm("v_cvt_pk_bf16_f32 %0, %1, %2" : "=v"(r) : "v"(lo), "v"(hi));
    return r;
}
// packed fp32x2 -> fp16x2 (RTZ), single instruction
__device__ __forceinline__ unsigned pkh2(float lo, float hi) {
    unsigned r;
    asm("v_cvt_pkrtz_f16_f32 %0, %1, %2" : "=v"(r) : "v"(lo), "v"(hi));
    return r;
}
__device__ __forceinline__ float blo(unsigned u) { return __uint_as_float(u << 16); }
__device__ __forceinline__ float bhi(unsigned u) { return __uint_as_float(u & 0xffff0000u); }
__device__ __forceinline__ float hlo(unsigned u) {
    return __half2float(__ushort_as_half((unsigned short)(u & 0xffffu)));
}
__device__ __forceinline__ float hhi(unsigned u) {
    return __half2float(__ushort_as_half((unsigned short)(u >> 16)));
}

__device__ __forceinline__ int load_idx(const void* ei, int f64, long long pos) {
    return f64 ? (int)((const long long*)ei)[pos] : ((const int*)ei)[pos];
}

// bucketed fill: esrc[dst*CAP + pos] (ushort; NN < 65536), cursor[] = degree.
__global__ void k_fill(const void* ei, const int* __restrict__ flag,
                       int* cursor, ushort_t* __restrict__ esrc) {
    int e = blockIdx.x * blockDim.x + threadIdx.x;
    if (e >= ETOT) return;
    int f = *flag;
    int src, dst;
    if (e < EE) {
        src = load_idx(ei, f, e);
        dst = load_idx(ei, f, (long long)EE + e);
    } else {
        src = dst = e - EE;
    }
    int pos = atomicAdd(&cursor[dst], 1);
    if (pos < CAP) esrc[dst * CAP + pos] = (ushort_t)src;
}

// Combined prep: Af swizzle, Wf (MFMA B lane order), b1s/W2s permute
// ([head][slot][kk]: kk<4 -> f=kk*16+2*slot ; kk>=4 -> f=(kk-4)*16+2*slot+1),
// edge-index width detect.
__global__ __launch_bounds__(256) void k_prep(const float* __restrict__ x,
                                              const float* __restrict__ W,
                                              const float* __restrict__ b1,
                                              const float* __restrict__ W2,
                                              const void* ei,
                                              bf16x8* __restrict__ Af,
                                              ushort_t* __restrict__ Wf,
                                              float* __restrict__ b1s,
                                              float* __restrict__ W2s,
                                              int* __restrict__ flag) {
    int bid = blockIdx.x, t = threadIdx.x;
    if (bid < NTILE) {
        int kt = t >> 6, lg = (t >> 4) & 3, lr = t & 15;
        int row = bid * 16 + lr;
        if (row >= NN) row = NN - 1;
        const float4* p = (const float4*)(x + (size_t)row * 128 + kt * 32 + lg * 8);
        float4 a = p[0], b = p[1];
        union { unsigned u[4]; bf16x8 v; } r;
        r.u[0] = cvtpk(a.x, a.y);
        r.u[1] = cvtpk(a.z, a.w);
        r.u[2] = cvtpk(b.x, b.y);
        r.u[3] = cvtpk(b.z, b.w);
        Af[(size_t)bid * 256 + t] = r.v;
        return;
    }
    int idx = (bid - NTILE) * 256 + t;
    if (idx < 32768) {
        int e = idx & 7, l = (idx >> 3) & 63, ct = (idx >> 9) & 15, kt = idx >> 13;
        int k = kt * 32 + (l >> 4) * 8 + e;
        int col = ct * 16 + (l & 15);
        Wf[idx] = (ushort_t)f2bf(W[k * 256 + col]);
    } else if (idx < 32768 + 256) {
        int c = idx - 32768;             // [head(2)][slot(3)][kk(3)]
        int head = c >> 6, slot = (c >> 3) & 7, kk = c & 7;
        int f = (kk < 4) ? (kk * 16 + 2 * slot) : ((kk - 4) * 16 + 2 * slot + 1);
        b1s[c] = b1[head * 64 + f];
        W2s[c] = W2[head * 64 + f];
    } else if (idx == 32768 + 256) {
        const long long* p = (const long long*)ei;
        int ok = 1;
        for (int i = 0; i < 64; ++i) {
            long long v = p[i];
            if (v < 0 || v >= NN) ok = 0;
        }
        *flag = ok;  // 1 -> int64, 0 -> int32
    }
}

// h = x @ W1 via mfma_f32_16x16x32_bf16. Block: 4 waves = 4 heads, 64 rows.
// Stores: HEAD-MAJOR h1h[head][row][uint2 x16] + interleaved float4 scores
// sS/sD [node][head] (for k_alpha's one-load gather).
__global__ __launch_bounds__(256) void k_gemm_mfma(
    const bf16x8* __restrict__ Af, const ushort_t* __restrict__ Wf,
    const float* __restrict__ aS, const float* __restrict__ aD,
    uint2* __restrict__ h1h, float* __restrict__ sS, float* __restrict__ sD) {
    int t = threadIdx.x, wid = t >> 6, l = t & 63;
    int lg = l >> 4, lr = l & 15;
    int r0 = blockIdx.x * 64;
    int tile0 = blockIdx.x * 4;
    int c0 = wid * 64;
    const bf16x8* Bv = (const bf16x8*)Wf;

    f32x4 acc[4][4] = {};
#pragma unroll
    for (int kt = 0; kt < 4; ++kt) {
        bf16x8 a[4];
#pragma unroll
        for (int rt = 0; rt < 4; ++rt)
            a[rt] = Af[(size_t)(((tile0 + rt) * 4 + kt) * 4 + lg) * 16 + lr];
#pragma unroll
        for (int ct = 0; ct < 4; ++ct) {
            bf16x8 b = Bv[(size_t)((kt * 16 + wid * 4 + ct) * 64 + l)];
#pragma unroll
            for (int rt = 0; rt < 4; ++rt)
                acc[rt][ct] = __builtin_amdgcn_mfma_f32_16x16x32_bf16(a[rt], b, acc[rt][ct], 0, 0, 0);
        }
    }
    float aSl[4], aDl[4];
#pragma unroll
    for (int ct = 0; ct < 4; ++ct) {
        aSl[ct] = aS[c0 + ct * 16 + lr];
        aDl[ct] = aD[c0 + ct * 16 + lr];
    }
#pragma unroll
    for (int rt = 0; rt < 4; ++rt) {
#pragma unroll
        for (int q = 0; q < 4; ++q) {
            int row = r0 + rt * 16 + lg * 4 + q;
            bool ok = row < NN;
            float v0 = acc[rt][0][q], v1 = acc[rt][1][q];
            float v2 = acc[rt][2][q], v3 = acc[rt][3][q];
            float p = v0 * aSl[0] + v1 * aSl[1] + v2 * aSl[2] + v3 * aSl[3];
            float dd = v0 * aDl[0] + v1 * aDl[1] + v2 * aDl[2] + v3 * aDl[3];
            uint2 u;
            u.x = cvtpk(v0, v1);
            u.y = cvtpk(v2, v3);
            if (ok) h1h[((size_t)wid * NN + row) * 16 + lr] = u;
#pragma unroll
            for (int k = 8; k >= 1; k >>= 1) {
                p += __shfl_xor(p, k, 64);
                dd += __shfl_xor(dd, k, 64);
            }
            if (ok && lr == 0) {
                sS[row * 4 + wid] = p;
                sD[row * 4 + wid] = dd;
            }
        }
    }
}

// per-node softmax for all 4 heads at once (4 exp per edge), writing
// NORMALIZED alpha (fp16, high 16) packed with src (low 16), head-major:
// alsrc[head][n*CAP + lane].
__global__ __launch_bounds__(256) void k_alpha(
    const int* __restrict__ cursor, const ushort_t* __restrict__ esrc,
    const float* __restrict__ sS, const float* __restrict__ sD,
    unsigned* __restrict__ alsrc) {
    int wid = threadIdx.x >> 6, lane = threadIdx.x & 63;
    int n = blockIdx.x * 4 + wid;
    if (n >= NN) return;
    int d = cursor[n];
    if (d > CAP) d = CAP;
    int dp = (d + 15) & ~15;
    float4 sd = *(const float4*)(sD + (size_t)n * 4);
    float e0 = -1e30f, e1 = -1e30f, e2 = -1e30f, e3 = -1e30f;
    int s = 0;
    if (lane < d) {
        s = esrc[n * CAP + lane];
        float4 ss = *(const float4*)(sS + (size_t)s * 4);
        e0 = ss.x + sd.x; e0 = e0 > 0.f ? e0 : NEG * e0;
        e1 = ss.y + sd.y; e1 = e1 > 0.f ? e1 : NEG * e1;
        e2 = ss.z + sd.z; e2 = e2 > 0.f ? e2 : NEG * e2;
        e3 = ss.w + sd.w; e3 = e3 > 0.f ? e3 : NEG * e3;
    }
    float m0 = e0, m1 = e1, m2 = e2, m3 = e3;
#pragma unroll
    for (int k = 32; k >= 1; k >>= 1) {
        m0 = fmaxf(m0, __shfl_xor(m0, k, 64));
        m1 = fmaxf(m1, __shfl_xor(m1, k, 64));
        m2 = fmaxf(m2, __shfl_xor(m2, k, 64));
        m3 = fmaxf(m3, __shfl_xor(m3, k, 64));
    }
    float x0 = __expf(e0 - m0);   // inactive lanes -> 0
    float x1 = __expf(e1 - m1);
    float x2 = __expf(e2 - m2);
    float x3 = __expf(e3 - m3);
    float q0 = x0, q1 = x1, q2 = x2, q3 = x3;
#pragma unroll
    for (int k = 32; k >= 1; k >>= 1) {
        q0 += __shfl_xor(q0, k, 64);
        q1 += __shfl_xor(q1, k, 64);
        q2 += __shfl_xor(q2, k, 64);
        q3 += __shfl_xor(q3, k, 64);
    }
    if (lane < dp) {
        unsigned su = (unsigned)s;
        float r0 = x0 / q0, r1 = x1 / q1, r2 = x2 / q2, r3 = x3 / q3;
        alsrc[(size_t)0 * NN * CAP + (size_t)n * CAP + lane] = (pkh2(r0, r0) & 0xffff0000u) | su;
        alsrc[(size_t)1 * NN * CAP + (size_t)n * CAP + lane] = (pkh2(r1, r1) & 0xffff0000u) | su;
        alsrc[(size_t)2 * NN * CAP + (size_t)n * CAP + lane] = (pkh2(r2, r2) & 0xffff0000u) | su;
        alsrc[(size_t)3 * NN * CAP + (size_t)n * CAP + lane] = (pkh2(r3, r3) & 0xffff0000u) | su;
    }
}

// HEAD-SPLIT weighted gather: one wave per (node, head), pure gather+FMA.
// blockIdx%8 -> XCD (measured round-robin); head = xcd>>1 pins each head's
// 6.4MB h-slice + its alsrc slice to an XCD pair. No softmax, no expm1,
// no atomics here. Output: aggH[head][n][64] fp16-packed (uint4 x8).
__global__ __launch_bounds__(256) void k_aggh(
    const int* __restrict__ cursor, const unsigned* __restrict__ alsrc,
    const uint4* __restrict__ h1h, uint4* __restrict__ aggH) {
    __shared__ unsigned as_lds[4][CAP];
    int b = blockIdx.x;
    int xcd = b & 7, head = xcd >> 1, sub = xcd & 1;
    int grp = b >> 3;
    int wid = threadIdx.x >> 6, lane = threadIdx.x & 63;
    int n = grp * 8 + sub * 4 + wid;   // NN % 8 == 0 -> always < NN
    int d = cursor[n];
    if (d > CAP) d = CAP;
    int dp = (d + 15) & ~15;
    unsigned u0 = 0;
    if (lane < dp) u0 = alsrc[(size_t)head * NN * CAP + (size_t)n * CAP + lane];
    as_lds[wid][lane] = u0;
    int slot = lane & 7, eg = lane >> 3;
    const uint4* hp = h1h + (size_t)head * NN * 8 + slot;
    float a0 = 0.f, a1 = 0.f, a2 = 0.f, a3 = 0.f;
    float a4 = 0.f, a5 = 0.f, a6 = 0.f, a7 = 0.f;
    for (int j = 0; j < dp; j += 16) {
        unsigned uA = as_lds[wid][j + eg];
        unsigned uB = as_lds[wid][j + 8 + eg];
        float wA = hhi(uA), wB = hhi(uB);
        int sA = (int)(uA & 0xffffu);
        int sB = (int)(uB & 0xffffu);
        uint4 hA = hp[(size_t)sA * 8];
        uint4 hB = hp[(size_t)sB * 8];
        a0 = fmaf(wA, blo(hA.x), a0); a1 = fmaf(wA, bhi(hA.x), a1);
        a2 = fmaf(wA, blo(hA.y), a2); a3 = fmaf(wA, bhi(hA.y), a3);
        a4 = fmaf(wA, blo(hA.z), a4); a5 = fmaf(wA, bhi(hA.z), a5);
        a6 = fmaf(wA, blo(hA.w), a6); a7 = fmaf(wA, bhi(hA.w), a7);
        a0 = fmaf(wB, blo(hB.x), a0); a1 = fmaf(wB, bhi(hB.x), a1);
        a2 = fmaf(wB, blo(hB.y), a2); a3 = fmaf(wB, bhi(hB.y), a3);
        a4 = fmaf(wB, blo(hB.z), a4); a5 = fmaf(wB, bhi(hB.z), a5);
        a6 = fmaf(wB, blo(hB.w), a6); a7 = fmaf(wB, bhi(hB.w), a7);
    }
    // combine the 8 edge groups (same slot)
    a0 += __shfl_xor(a0, 8, 64);  a0 += __shfl_xor(a0, 16, 64); a0 += __shfl_xor(a0, 32, 64);
    a1 += __shfl_xor(a1, 8, 64);  a1 += __shfl_xor(a1, 16, 64); a1 += __shfl_xor(a1, 32, 64);
    a2 += __shfl_xor(a2, 8, 64);  a2 += __shfl_xor(a2, 16, 64); a2 += __shfl_xor(a2, 32, 64);
    a3 += __shfl_xor(a3, 8, 64);  a3 += __shfl_xor(a3, 16, 64); a3 += __shfl_xor(a3, 32, 64);
    a4 += __shfl_xor(a4, 8, 64);  a4 += __shfl_xor(a4, 16, 64); a4 += __shfl_xor(a4, 32, 64);
    a5 += __shfl_xor(a5, 8, 64);  a5 += __shfl_xor(a5, 16, 64); a5 += __shfl_xor(a5, 32, 64);
    a6 += __shfl_xor(a6, 8, 64);  a6 += __shfl_xor(a6, 16, 64); a6 += __shfl_xor(a6, 32, 64);
    a7 += __shfl_xor(a7, 8, 64);  a7 += __shfl_xor(a7, 16, 64); a7 += __shfl_xor(a7, 32, 64);
    if (eg == 0) {
        uint4 o;
        o.x = pkh2(a0, a1);
        o.y = pkh2(a2, a3);
        o.z = pkh2(a4, a5);
        o.w = pkh2(a6, a7);
        aggH[((size_t)head * NN + n) * 8 + slot] = o;
    }
}

// finish layer 1: read 4 head slices, +b1 -> ELU -> dot W2 -> g[n].
// lane l -> head l>>4, uint2 (l&15) of the slice; b1s/W2s float4 index = l.
__global__ __launch_bounds__(256) void k_fin(
    const uint2* __restrict__ aggH2, const float* __restrict__ b1s,
    const float* __restrict__ W2s, float* __restrict__ g) {
    int wid = threadIdx.x >> 6, lane = threadIdx.x & 63;
    int n = blockIdx.x * 4 + wid;
    if (n >= NN) return;
    int head = lane >> 4, r = lane & 15;
    uint2 q = aggH2[((size_t)head * NN + n) * 16 + r];
    float4 bv = ((const float4*)b1s)[lane];
    float4 wv = ((const float4*)W2s)[lane];
    float o0 = hlo(q.x) + bv.x;
    float o1 = hhi(q.x) + bv.y;
    float o2 = hlo(q.y) + bv.z;
    float o3 = hhi(q.y) + bv.w;
    o0 = o0 > 0.f ? o0 : expm1f(o0);
    o1 = o1 > 0.f ? o1 : expm1f(o1);
    o2 = o2 > 0.f ? o2 : expm1f(o2);
    o3 = o3 > 0.f ? o3 : expm1f(o3);
    float part = o0 * wv.x + o1 * wv.y + o2 * wv.z + o3 * wv.w;
#pragma unroll
    for (int k = 32; k >= 1; k >>= 1) part += __shfl_xor(part, k, 64);
    if (lane == 0) g[n] = part;
}

// layer 2: scalar attention, one wave per dst node, one edge per lane.
__global__ __launch_bounds__(256) void k_layer2(
    const int* __restrict__ cursor, const ushort_t* __restrict__ esrc,
    const float* __restrict__ g, const float* __restrict__ aS2,
    const float* __restrict__ aD2, const float* __restrict__ b2,
    float* __restrict__ out) {
    int wid = threadIdx.x >> 6, lane = threadIdx.x & 63;
    int n = blockIdx.x * 4 + wid;
    if (n >= NN) return;
    int d = cursor[n];
    if (d > CAP) d = CAP;
    float aS = aS2[0], aD = aD2[0];
    float dn = g[n] * aD;
    float gv = 0.f, e = -1e30f;
    if (lane < d) {
        gv = g[esrc[n * CAP + lane]];
        e = gv * aS + dn;
        e = e > 0.f ? e : NEG * e;
    }
    float m = e;
#pragma unroll
    for (int k = 32; k >= 1; k >>= 1) m = fmaxf(m, __shfl_xor(m, k, 64));
    float ex = (lane < d) ? __expf(e - m) : 0.f;
    float den = ex, ws = ex * gv;
#pragma unroll
    for (int k = 32; k >= 1; k >>= 1) {
        den += __shfl_xor(den, k, 64);
        ws += __shfl_xor(ws, k, 64);
    }
    if (lane == 0) out[n] = ws / den + b2[0];
}

extern "C" void kernel_launch(void* const* d_in, const int* in_sizes, int n_in,
                              void* d_out, int out_size, void* d_ws, size_t ws_size,
                              hipStream_t stream) {
    const float* x   = (const float*)d_in[0];
    const void*  ei  = d_in[1];
    const float* W1  = (const float*)d_in[2];
    const float* aS1 = (const float*)d_in[3];
    const float* aD1 = (const float*)d_in[4];
    const float* b1  = (const float*)d_in[5];
    const float* W2  = (const float*)d_in[6];
    const float* aS2 = (const float*)d_in[7];
    const float* aD2 = (const float*)d_in[8];
    const float* b2  = (const float*)d_in[9];
    float* out = (float*)d_out;

    char* w = (char*)d_ws;
    size_t off = 0;
    auto take = [&](size_t bytes) {
        char* p = w + off;
        off = (off + bytes + 255) & ~(size_t)255;
        return p;
    };
    int*      flag   = (int*)take(4);
    int*      cursor = (int*)take((size_t)NN * 4);
    ushort_t* esrc   = (ushort_t*)take((size_t)NN * CAP * 2);
    float*    sS     = (float*)take((size_t)NN * 4 * 4);
    float*    sD     = (float*)take((size_t)NN * 4 * 4);
    float*    g      = (float*)take((size_t)NN * 4);
    void*     h1h    = take((size_t)4 * NN * 128);       // head-major bf16 slices
    bf16x8*   Af     = (bf16x8*)take((size_t)NTILE * 256 * 16);
    ushort_t* Wf     = (ushort_t*)take((size_t)128 * 256 * 2);
    float*    b1s    = (float*)take((size_t)256 * 4);
    float*    W2s    = (float*)take((size_t)256 * 4);
    unsigned* alsrc  = (unsigned*)take((size_t)4 * NN * CAP * 4);  // fp16 alpha | src
    void*     aggH   = take((size_t)4 * NN * 128);       // fp16 agg slices
    (void)ws_size; (void)in_sizes; (void)n_in; (void)out_size;

    (void)hipMemsetAsync(cursor, 0, (size_t)NN * 4, stream);
    k_prep<<<NTILE + 130, 256, 0, stream>>>(x, W1, b1, W2, ei, Af, Wf, b1s, W2s, flag);
    k_fill<<<(ETOT + 255) / 256, 256, 0, stream>>>(ei, flag, cursor, esrc);
    k_gemm_mfma<<<NBLK, 256, 0, stream>>>(Af, Wf, aS1, aD1, (uint2*)h1h, sS, sD);
    k_alpha<<<(NN + 3) / 4, 256, 0, stream>>>(cursor, esrc, sS, sD, alsrc);
    k_aggh<<<NN, 256, 0, stream>>>(cursor, alsrc, (const uint4*)h1h, (uint4*)aggH);
    k_fin<<<(NN + 3) / 4, 256, 0, stream>>>((const uint2*)aggH, b1s, W2s, g);
    k_layer2<<<(NN + 3) / 4, 256, 0, stream>>>(cursor, esrc, g, aS2, aD2, b2, out);
}

// Round 11
// 187.087 us; speedup vs baseline: 1.1761x; 1.0894x over previous
//
#include <hip/hip_runtime.h>
#include <math.h>

#define NN 50000
#define EE 800000
#define ETOT 850000
#define NEG 0.2f
#define CAP 64      // per-node edge bucket capacity; P(deg>64) ~ 1e-18 for Poisson(16)+1
#define NBLK 782    // gemm blocks (64 rows each)
#define FBLK 3321   // fill blocks (256 edges each)

typedef unsigned short ushort_t;
typedef __attribute__((ext_vector_type(8))) short bf16x8;   // 8 bf16 (4 VGPRs)
typedef __attribute__((ext_vector_type(4))) float f32x4;    // MFMA accumulator

__device__ __forceinline__ unsigned f2bf(float f) {
    unsigned u = __float_as_uint(f);
    return (u + 0x7FFFu + ((u >> 16) & 1u)) >> 16;
}
// packed fp32x2 -> bf16x2 (RNE), single instruction
__device__ __forceinline__ unsigned cvtpk(float lo, float hi) {
    unsigned r;
    asm("v_cvt_pk_bf16_f32 %0, %1, %2" : "=v"(r) : "v"(lo), "v"(hi));
    return r;
}
__device__ __forceinline__ float blo(unsigned u) { return __uint_as_float(u << 16); }
__device__ __forceinline__ float bhi(unsigned u) { return __uint_as_float(u & 0xffff0000u); }

__device__ __forceinline__ int load_idx(const void* ei, int f64, long long pos) {
    return f64 ? (int)((const long long*)ei)[pos] : ((const int*)ei)[pos];
}

// Prep: Wf (MFMA B lane order), b1q/W2q permute (uint4-gather chunk order),
// edge-index width detect, AND cursor zeroing (replaces hipMemsetAsync).
__global__ __launch_bounds__(256) void k_prep(const float* __restrict__ W,
                                              const float* __restrict__ b1,
                                              const float* __restrict__ W2,
                                              const void* ei,
                                              ushort_t* __restrict__ Wf,
                                              float* __restrict__ b1q,
                                              float* __restrict__ W2q,
                                              int* __restrict__ flag,
                                              int* __restrict__ cursor) {
    int bid = blockIdx.x, t = threadIdx.x;
    if (bid < 128) {
        int idx = bid * 256 + t;
        int e = idx & 7, l = (idx >> 3) & 63, ct = (idx >> 9) & 15, kt = idx >> 13;
        int k = kt * 32 + (l >> 4) * 8 + e;
        int col = ct * 16 + (l & 15);
        Wf[idx] = (ushort_t)f2bf(W[k * 256 + col]);
    } else if (bid == 128) {
        if (t < 64) {
            int c = t;                    // chunk id 0..63
            int hl = c >> 1, sub = c & 1, head = c >> 4, lrr = c & 15;
#pragma unroll
            for (int kk = 0; kk < 4; ++kk) {
                b1q[hl * 8 + sub * 4 + kk] = b1[head * 64 + lrr + 16 * kk];
                W2q[hl * 8 + sub * 4 + kk] = W2[head * 64 + lrr + 16 * kk];
            }
        } else if (t == 64) {
            const long long* p = (const long long*)ei;
            int ok = 1;
            for (int i = 0; i < 64; ++i) {
                long long v = p[i];
                if (v < 0 || v >= NN) ok = 0;
            }
            *flag = ok;  // 1 -> int64, 0 -> int32
        }
    } else {
        int idx = (bid - 129) * 256 + t;  // zero cursor as int4
        if (idx < NN / 4) ((int4*)cursor)[idx] = make_int4(0, 0, 0, 0);
    }
}

// Fused mid-stage: blocks [0,NBLK) = MFMA GEMM (x LDS-staged, converted to
// bf16 in LDS; one ds_read_b128 per A-fragment); blocks [NBLK,NBLK+FBLK) =
// bucketed edge fill (latency-bound atomics co-scheduled with the GEMM).
__global__ __launch_bounds__(256) void k_main(
    const float* __restrict__ x, const ushort_t* __restrict__ Wf,
    const float* __restrict__ aS, const float* __restrict__ aD,
    const void* ei, const int* __restrict__ flag,
    int* cursor, ushort_t* __restrict__ esrc,
    uint2* __restrict__ h1c, float* __restrict__ sS, float* __restrict__ sD) {
    __shared__ ushort_t xs[64][144];   // 64 rows x 128 bf16, +16 pad shorts
    int bid = blockIdx.x, t = threadIdx.x;
    if (bid >= NBLK) {
        // ---- fill path
        int e = (bid - NBLK) * 256 + t;
        if (e >= ETOT) return;
        int f = *flag;
        int src, dst;
        if (e < EE) {
            src = load_idx(ei, f, e);
            dst = load_idx(ei, f, (long long)EE + e);
        } else {
            src = dst = e - EE;
        }
        int pos = atomicAdd(&cursor[dst], 1);
        if (pos < CAP) esrc[dst * CAP + pos] = (ushort_t)src;
        return;
    }
    // ---- gemm path
    int wid = t >> 6, l = t & 63;
    int lg = l >> 4, lr = l & 15;
    int r0 = bid * 64;
    int c0 = wid * 64;
    // stage x rows r0..r0+63 into LDS as bf16 (coalesced: 16 lanes per row)
    for (int i = t; i < 1024; i += 256) {
        int row = i >> 4, c = i & 15;
        int gr = r0 + row;
        if (gr >= NN) gr = NN - 1;
        const float4* p = (const float4*)(x + (size_t)gr * 128 + c * 8);
        float4 a = p[0], b = p[1];
        uint4 v;
        v.x = cvtpk(a.x, a.y);
        v.y = cvtpk(a.z, a.w);
        v.z = cvtpk(b.x, b.y);
        v.w = cvtpk(b.z, b.w);
        *(uint4*)&xs[row][c * 8] = v;
    }
    __syncthreads();
    const bf16x8* Bv = (const bf16x8*)Wf;
    f32x4 acc[4][4] = {};
#pragma unroll
    for (int kt = 0; kt < 4; ++kt) {
        bf16x8 a[4];
#pragma unroll
        for (int rt = 0; rt < 4; ++rt)
            a[rt] = *(const bf16x8*)&xs[rt * 16 + lr][kt * 32 + lg * 8];
#pragma unroll
        for (int ct = 0; ct < 4; ++ct) {
            bf16x8 b = Bv[(size_t)((kt * 16 + wid * 4 + ct) * 64 + l)];
#pragma unroll
            for (int rt = 0; rt < 4; ++rt)
                acc[rt][ct] = __builtin_amdgcn_mfma_f32_16x16x32_bf16(a[rt], b, acc[rt][ct], 0, 0, 0);
        }
    }
    // epilogue. C/D layout: col = c0+ct*16+lr, row = r0+rt*16+lg*4+q
    float aSl[4], aDl[4];
#pragma unroll
    for (int ct = 0; ct < 4; ++ct) {
        aSl[ct] = aS[c0 + ct * 16 + lr];
        aDl[ct] = aD[c0 + ct * 16 + lr];
    }
#pragma unroll
    for (int rt = 0; rt < 4; ++rt) {
#pragma unroll
        for (int q = 0; q < 4; ++q) {
            int row = r0 + rt * 16 + lg * 4 + q;
            bool ok = row < NN;
            float v0 = acc[rt][0][q], v1 = acc[rt][1][q];
            float v2 = acc[rt][2][q], v3 = acc[rt][3][q];
            float p = v0 * aSl[0] + v1 * aSl[1] + v2 * aSl[2] + v3 * aSl[3];
            float dd = v0 * aDl[0] + v1 * aDl[1] + v2 * aDl[2] + v3 * aDl[3];
            uint2 u;
            u.x = cvtpk(v0, v1);
            u.y = cvtpk(v2, v3);
            if (ok) h1c[(size_t)row * 64 + wid * 16 + lr] = u;
#pragma unroll
            for (int k = 8; k >= 1; k >>= 1) {
                p += __shfl_xor(p, k, 64);
                dd += __shfl_xor(dd, k, 64);
            }
            if (ok && lr == 0) {
                sS[row * 4 + wid] = p;
                sD[row * 4 + wid] = dd;
            }
        }
    }
}

// layer-1 aggregation (r6/r7 monolith), one wave per dst node.
// Pass 1: per-lane edge scores -> wave max/exp/sum -> normalized alpha in LDS.
// Pass 2: uint4 (16B) gathers; 32 lanes per edge row, wave covers 2 edges/load.
// Epilogue: + b1q -> ELU -> dot W2q -> reduce -> g[n].
// `base` allows splitting the grid into sub-dispatches (profiling visibility).
__global__ __launch_bounds__(256) void k_agg1(
    const int* __restrict__ cursor, const ushort_t* __restrict__ esrc,
    const uint4* __restrict__ h1c4, const float* __restrict__ sS,
    const float* __restrict__ sD, const float* __restrict__ b1q,
    const float* __restrict__ W2q, float* __restrict__ g, int base) {
    __shared__ float al_lds[4][CAP][4];
    __shared__ int s_lds[4][CAP];
    int wid = threadIdx.x >> 6, lane = threadIdx.x & 63;
    int n = base + blockIdx.x * 4 + wid;
    if (n >= NN) return;
    int d = cursor[n];
    if (d > CAP) d = CAP;
    int dp = (d + 7) & ~7;  // pad to x8; pad slots have alpha=0, s=0
    float4 sd = *(const float4*)(sD + (size_t)n * 4);
    float e0 = -1e30f, e1 = -1e30f, e2 = -1e30f, e3 = -1e30f;
    int s = 0;
    if (lane < d) {
        s = esrc[n * CAP + lane];
        float4 ss = *(const float4*)(sS + (size_t)s * 4);
        e0 = ss.x + sd.x; e0 = e0 > 0.f ? e0 : NEG * e0;
        e1 = ss.y + sd.y; e1 = e1 > 0.f ? e1 : NEG * e1;
        e2 = ss.z + sd.z; e2 = e2 > 0.f ? e2 : NEG * e2;
        e3 = ss.w + sd.w; e3 = e3 > 0.f ? e3 : NEG * e3;
    }
    float m0 = e0, m1 = e1, m2 = e2, m3 = e3;
#pragma unroll
    for (int k = 32; k >= 1; k >>= 1) {
        m0 = fmaxf(m0, __shfl_xor(m0, k, 64));
        m1 = fmaxf(m1, __shfl_xor(m1, k, 64));
        m2 = fmaxf(m2, __shfl_xor(m2, k, 64));
        m3 = fmaxf(m3, __shfl_xor(m3, k, 64));
    }
    float x0 = __expf(e0 - m0);  // inactive lanes: exp(-huge)=0
    float x1 = __expf(e1 - m1);
    float x2 = __expf(e2 - m2);
    float x3 = __expf(e3 - m3);
    float q0 = x0, q1 = x1, q2 = x2, q3 = x3;
#pragma unroll
    for (int k = 32; k >= 1; k >>= 1) {
        q0 += __shfl_xor(q0, k, 64);
        q1 += __shfl_xor(q1, k, 64);
        q2 += __shfl_xor(q2, k, 64);
        q3 += __shfl_xor(q3, k, 64);
    }
    if (lane < dp) {
        al_lds[wid][lane][0] = x0 / q0;
        al_lds[wid][lane][1] = x1 / q1;
        al_lds[wid][lane][2] = x2 / q2;
        al_lds[wid][lane][3] = x3 / q3;
        s_lds[wid][lane] = s;
    }
    __builtin_amdgcn_s_barrier();
    // pass 2
    int hl = lane & 31, p = lane >> 5;
    int head = hl >> 3;
    float a0 = 0.f, a1 = 0.f, a2 = 0.f, a3 = 0.f;
    float a4 = 0.f, a5 = 0.f, a6 = 0.f, a7 = 0.f;
    for (int j = 0; j < dp; j += 8) {
        int i0 = j + p, i1 = j + 2 + p, i2 = j + 4 + p, i3 = j + 6 + p;
        int s0 = s_lds[wid][i0];
        int s1 = s_lds[wid][i1];
        int s2 = s_lds[wid][i2];
        int s3 = s_lds[wid][i3];
        float w0 = al_lds[wid][i0][head];
        float w1 = al_lds[wid][i1][head];
        float w2 = al_lds[wid][i2][head];
        float w3 = al_lds[wid][i3][head];
        uint4 u0 = h1c4[(size_t)s0 * 32 + hl];
        uint4 u1 = h1c4[(size_t)s1 * 32 + hl];
        uint4 u2 = h1c4[(size_t)s2 * 32 + hl];
        uint4 u3 = h1c4[(size_t)s3 * 32 + hl];
        a0 = fmaf(w0, blo(u0.x), a0); a1 = fmaf(w0, bhi(u0.x), a1);
        a2 = fmaf(w0, blo(u0.y), a2); a3 = fmaf(w0, bhi(u0.y), a3);
        a4 = fmaf(w0, blo(u0.z), a4); a5 = fmaf(w0, bhi(u0.z), a5);
        a6 = fmaf(w0, blo(u0.w), a6); a7 = fmaf(w0, bhi(u0.w), a7);
        a0 = fmaf(w1, blo(u1.x), a0); a1 = fmaf(w1, bhi(u1.x), a1);
        a2 = fmaf(w1, blo(u1.y), a2); a3 = fmaf(w1, bhi(u1.y), a3);
        a4 = fmaf(w1, blo(u1.z), a4); a5 = fmaf(w1, bhi(u1.z), a5);
        a6 = fmaf(w1, blo(u1.w), a6); a7 = fmaf(w1, bhi(u1.w), a7);
        a0 = fmaf(w2, blo(u2.x), a0); a1 = fmaf(w2, bhi(u2.x), a1);
        a2 = fmaf(w2, blo(u2.y), a2); a3 = fmaf(w2, bhi(u2.y), a3);
        a4 = fmaf(w2, blo(u2.z), a4); a5 = fmaf(w2, bhi(u2.z), a5);
        a6 = fmaf(w2, blo(u2.w), a6); a7 = fmaf(w2, bhi(u2.w), a7);
        a0 = fmaf(w3, blo(u3.x), a0); a1 = fmaf(w3, bhi(u3.x), a1);
        a2 = fmaf(w3, blo(u3.y), a2); a3 = fmaf(w3, bhi(u3.y), a3);
        a4 = fmaf(w3, blo(u3.z), a4); a5 = fmaf(w3, bhi(u3.z), a5);
        a6 = fmaf(w3, blo(u3.w), a6); a7 = fmaf(w3, bhi(u3.w), a7);
    }
    // combine the two half-wave edge partitions
    a0 += __shfl_xor(a0, 32, 64); a1 += __shfl_xor(a1, 32, 64);
    a2 += __shfl_xor(a2, 32, 64); a3 += __shfl_xor(a3, 32, 64);
    a4 += __shfl_xor(a4, 32, 64); a5 += __shfl_xor(a5, 32, 64);
    a6 += __shfl_xor(a6, 32, 64); a7 += __shfl_xor(a7, 32, 64);
    // epilogue (alpha pre-normalized; no division)
    float4 bA = ((const float4*)b1q)[hl * 2];
    float4 bB = ((const float4*)b1q)[hl * 2 + 1];
    float4 wA = ((const float4*)W2q)[hl * 2];
    float4 wB = ((const float4*)W2q)[hl * 2 + 1];
    float o0 = a0 + bA.x, o1 = a1 + bA.y, o2 = a2 + bA.z, o3 = a3 + bA.w;
    float o4 = a4 + bB.x, o5 = a5 + bB.y, o6 = a6 + bB.z, o7 = a7 + bB.w;
    o0 = o0 > 0.f ? o0 : expm1f(o0);
    o1 = o1 > 0.f ? o1 : expm1f(o1);
    o2 = o2 > 0.f ? o2 : expm1f(o2);
    o3 = o3 > 0.f ? o3 : expm1f(o3);
    o4 = o4 > 0.f ? o4 : expm1f(o4);
    o5 = o5 > 0.f ? o5 : expm1f(o5);
    o6 = o6 > 0.f ? o6 : expm1f(o6);
    o7 = o7 > 0.f ? o7 : expm1f(o7);
    float part = o0 * wA.x + o1 * wA.y + o2 * wA.z + o3 * wA.w
               + o4 * wB.x + o5 * wB.y + o6 * wB.z + o7 * wB.w;
#pragma unroll
    for (int k = 16; k >= 1; k >>= 1) part += __shfl_xor(part, k, 64);
    if (lane == 0) g[n] = part;
}

// layer 2: scalar attention, one wave per dst node, one edge per lane.
__global__ __launch_bounds__(256) void k_layer2(
    const int* __restrict__ cursor, const ushort_t* __restrict__ esrc,
    const float* __restrict__ g, const float* __restrict__ aS2,
    const float* __restrict__ aD2, const float* __restrict__ b2,
    float* __restrict__ out) {
    int wid = threadIdx.x >> 6, lane = threadIdx.x & 63;
    int n = blockIdx.x * 4 + wid;
    if (n >= NN) return;
    int d = cursor[n];
    if (d > CAP) d = CAP;
    float aS = aS2[0], aD = aD2[0];
    float dn = g[n] * aD;
    float gv = 0.f, e = -1e30f;
    if (lane < d) {
        gv = g[esrc[n * CAP + lane]];
        e = gv * aS + dn;
        e = e > 0.f ? e : NEG * e;
    }
    float m = e;
#pragma unroll
    for (int k = 32; k >= 1; k >>= 1) m = fmaxf(m, __shfl_xor(m, k, 64));
    float ex = (lane < d) ? __expf(e - m) : 0.f;
    float den = ex, ws = ex * gv;
#pragma unroll
    for (int k = 32; k >= 1; k >>= 1) {
        den += __shfl_xor(den, k, 64);
        ws += __shfl_xor(ws, k, 64);
    }
    if (lane == 0) out[n] = ws / den + b2[0];
}

extern "C" void kernel_launch(void* const* d_in, const int* in_sizes, int n_in,
                              void* d_out, int out_size, void* d_ws, size_t ws_size,
                              hipStream_t stream) {
    const float* x   = (const float*)d_in[0];
    const void*  ei  = d_in[1];
    const float* W1  = (const float*)d_in[2];
    const float* aS1 = (const float*)d_in[3];
    const float* aD1 = (const float*)d_in[4];
    const float* b1  = (const float*)d_in[5];
    const float* W2  = (const float*)d_in[6];
    const float* aS2 = (const float*)d_in[7];
    const float* aD2 = (const float*)d_in[8];
    const float* b2  = (const float*)d_in[9];
    float* out = (float*)d_out;

    char* w = (char*)d_ws;
    size_t off = 0;
    auto take = [&](size_t bytes) {
        char* p = w + off;
        off = (off + bytes + 255) & ~(size_t)255;
        return p;
    };
    int*      flag   = (int*)take(4);
    int*      cursor = (int*)take((size_t)NN * 4);
    ushort_t* esrc   = (ushort_t*)take((size_t)NN * CAP * 2);
    float*    sS     = (float*)take((size_t)NN * 4 * 4);
    float*    sD     = (float*)take((size_t)NN * 4 * 4);
    float*    g      = (float*)take((size_t)NN * 4);
    void*     h1c    = take((size_t)NN * 64 * 8);   // written uint2[64], read uint4[32]
    ushort_t* Wf     = (ushort_t*)take((size_t)128 * 256 * 2);
    float*    b1q    = (float*)take((size_t)256 * 4);
    float*    W2q    = (float*)take((size_t)256 * 4);
    (void)ws_size; (void)in_sizes; (void)n_in; (void)out_size;

    // 129 blocks (Wf + small tables + detect) + 49 blocks (cursor zero)
    k_prep<<<178, 256, 0, stream>>>(W1, b1, W2, ei, Wf, b1q, W2q, flag, cursor);
    // fused GEMM (LDS-staged x) + edge fill
    k_main<<<NBLK + FBLK, 256, 0, stream>>>(x, Wf, aS1, aD1, ei, flag,
                                            cursor, esrc, (uint2*)h1c, sS, sD);
    // aggregation in 4 quarter-dispatches (profiling visibility; same work)
    for (int qtr = 0; qtr < 4; ++qtr)
        k_agg1<<<3125, 256, 0, stream>>>(cursor, esrc, (const uint4*)h1c,
                                         sS, sD, b1q, W2q, g, qtr * 12500);
    k_layer2<<<12500, 256, 0, stream>>>(cursor, esrc, g, aS2, aD2, b2, out);
}